// Round 7
// baseline (307.465 us; speedup 1.0000x reference)
//
#include <hip/hip_runtime.h>
#include <stdint.h>

// Problem constants
#define B_   20
#define S_   4096
#define E_   256
#define NB_  32
#define M_   (B_ * S_)          // 81920 rows

// ws layout (bytes)
#define OFF_Q   41943040ull
#define OFF_K   83886080ull
#define OFF_V   125829120ull    // vT bf16 [B][E][S]
#define OFF_WT  167772160ull    // WqT,WkT,WvT,WoT bf16, 131072 B each

typedef __attribute__((ext_vector_type(4))) float f32x4;
typedef __attribute__((ext_vector_type(8))) short short8;   // 8 x bf16
typedef __attribute__((ext_vector_type(4))) float float4v;
typedef __attribute__((ext_vector_type(4))) unsigned short us4;

__device__ __forceinline__ unsigned short f2bf(float f) {
  unsigned int u = __builtin_bit_cast(unsigned int, f);
  u += 0x7FFFu + ((u >> 16) & 1u);            // RNE
  return (unsigned short)(u >> 16);
}

__device__ __forceinline__ void glds16(const void* g, void* l) {
  __builtin_amdgcn_global_load_lds(
      (const __attribute__((address_space(1))) unsigned int*)g,
      (__attribute__((address_space(3))) unsigned int*)l, 16, 0, 0);
}

// ---------------- K0: weights fp32 -> bf16 TRANSPOSED, tiled ----------------
__global__ void k_convert_w(const float* __restrict__ Wq, const float* __restrict__ Wk,
                            const float* __restrict__ Wv, const float* __restrict__ Wo,
                            unsigned short* __restrict__ WT) {
  __shared__ float T[64][65];                    // +1 pad
  int g = blockIdx.x;
  int m = g >> 4, t = g & 15;
  int k0 = (t >> 2) * 64, n0 = (t & 3) * 64;
  const float* src = (m == 0) ? Wq : (m == 1) ? Wk : (m == 2) ? Wv : Wo;
  unsigned short* dst = WT + (size_t)m * 65536;
  int tid = threadIdx.x;
#pragma unroll
  for (int it = 0; it < 4; ++it) {               // read 64x64 fp32, coalesced float4
    int idx = it * 256 + tid;
    int kr = idx >> 4, nc = idx & 15;
    float4v v = *(const float4v*)(src + (size_t)(k0 + kr) * 256 + n0 + nc * 4);
    T[kr][nc * 4 + 0] = v[0]; T[kr][nc * 4 + 1] = v[1];
    T[kr][nc * 4 + 2] = v[2]; T[kr][nc * 4 + 3] = v[3];
  }
  __syncthreads();
#pragma unroll
  for (int it = 0; it < 2; ++it) {               // write transposed bf16, 16B coalesced
    int idx = it * 256 + tid;
    int nr = idx >> 3, kc = idx & 7;
    short8 o;
#pragma unroll
    for (int e = 0; e < 8; ++e) o[e] = (short)f2bf(T[kc * 8 + e][nr]);
    *(short8*)(dst + (size_t)(n0 + nr) * 256 + k0 + kc * 8) = o;
  }
}

// ---------------- K1: fused convert + QKV GEMM ----------------
// 640 blocks (one per 128-row x-tile, XCD-chunked), 4 waves; each wave owns 32 rows
// x 128 cols. A-fragments: loaded ONCE directly from fp32 x and converted in-register
// (x read exactly once; no xb intermediate). ct-loop over 6 output tiles (q0,q1,k0,
// k1,v0,v1) reuses resident A-frags; B (W^T) staged via glds16 double-buffer with
// counted vmcnt. All epilogues go through a 32KB LDS tile -> fully coalesced 16B
// stores in 256B chunks (q/k row-major; v transposed into vT[b][feat][s]).
__global__ __launch_bounds__(256, 2) void k_qkv(const float* __restrict__ x,
                                                const unsigned short* __restrict__ WT,
                                                unsigned short* __restrict__ qk,
                                                unsigned short* __restrict__ vT) {
  __shared__ char Bl[2][16384];     // B chunk [128 cols][64 K] bf16, swizzled
  __shared__ char Cl[32768];        // epilogue staging 128x128 bf16, swizzled

  int g = blockIdx.x;
  int rt = (g & 7) * 80 + (g >> 3);              // XCD-chunked, 80 row-tiles per XCD
  int tid = threadIdx.x, w = tid >> 6, l = tid & 63;
  int wr = w * 32;                                // wave's 32 rows
  int hi16 = (l >> 4) * 16;
  const char* WTc = (const char*)WT;

  // ---- A-frags direct from fp32 x (once), converted in-register ----
  short8 a[2][8];                                 // [row-block i][k-slice ks]
  const float* xb0 = x + (size_t)rt * 128 * 256;
#pragma unroll
  for (int i = 0; i < 2; ++i) {
    const float* xr = xb0 + (size_t)(wr + 16 * i + (l & 15)) * 256 + (l >> 4) * 8;
#pragma unroll
    for (int ks = 0; ks < 8; ++ks) {
      float4v v0 = *(const float4v*)(xr + ks * 32);
      float4v v1 = *(const float4v*)(xr + ks * 32 + 4);
      short8 t;
      t[0] = (short)f2bf(v0[0]); t[1] = (short)f2bf(v0[1]);
      t[2] = (short)f2bf(v0[2]); t[3] = (short)f2bf(v0[3]);
      t[4] = (short)f2bf(v1[0]); t[5] = (short)f2bf(v1[1]);
      t[6] = (short)f2bf(v1[2]); t[7] = (short)f2bf(v1[3]);
      a[i][ks] = t;
    }
  }

  auto STAGE_B = [&](int ct, int s, int bufi) {   // 16 KB, 4 glds16 per thread
    const char* Bb = WTc + (ct >> 1) * 131072 + (ct & 1) * 65536;
    char* dst = Bl[bufi];
#pragma unroll
    for (int j4 = 0; j4 < 4; ++j4) {
      int d = (j4 * 256 + tid) * 16;
      int row = d >> 7;
      int cx = (d & 127) ^ ((row & 7) << 4);      // pre-swizzled source (G21)
      glds16(Bb + (size_t)row * 512 + s * 128 + cx, dst + d);
    }
  };

  STAGE_B(0, 0, 0);

#pragma unroll
  for (int ct = 0; ct < 6; ++ct) {
    f32x4 acc[2][8];
#pragma unroll
    for (int i = 0; i < 2; ++i)
#pragma unroll
      for (int j = 0; j < 8; ++j) acc[i][j] = (f32x4){0.f, 0.f, 0.f, 0.f};

#pragma unroll
    for (int s = 0; s < 4; ++s) {
      int u = ct * 4 + s;
      if (u < 23) {
        STAGE_B((u + 1) >> 2, (u + 1) & 3, (u + 1) & 1);
        asm volatile("s_waitcnt vmcnt(4)" ::: "memory");   // stage u's 4 loads landed
      } else {
        asm volatile("s_waitcnt vmcnt(0)" ::: "memory");
      }
      __builtin_amdgcn_sched_barrier(0);
      __builtin_amdgcn_s_barrier();
      const char* bl = Bl[u & 1];
#pragma unroll
      for (int ksl = 0; ksl < 2; ++ksl) {
        short8 bfr[8];
#pragma unroll
        for (int j = 0; j < 8; ++j) {
          int rb = 16 * j + (l & 15);
          bfr[j] = *(const short8*)(bl + rb * 128 + ((ksl * 64 + hi16) ^ ((rb & 7) << 4)));
        }
        __builtin_amdgcn_s_setprio(1);
#pragma unroll
        for (int i = 0; i < 2; ++i)
#pragma unroll
          for (int j = 0; j < 8; ++j)
            acc[i][j] = __builtin_amdgcn_mfma_f32_16x16x32_bf16(a[i][s * 2 + ksl], bfr[j],
                                                                acc[i][j], 0, 0, 0);
        __builtin_amdgcn_s_setprio(0);
      }
      asm volatile("s_waitcnt lgkmcnt(0)" ::: "memory");
      __builtin_amdgcn_sched_barrier(0);
      __builtin_amdgcn_s_barrier();               // buffer free for next STAGE
    }

    // ---- epilogue via Cl: C/D layout col = lane&15, row = (lane>>4)*4 + r [m89] ----
    int mat = ct >> 1, col0 = (ct & 1) * 128;
    if (mat < 2) {
      // Cl[row 0..127][col byte 0..255], swizzled by row
#pragma unroll
      for (int i = 0; i < 2; ++i)
#pragma unroll
        for (int j = 0; j < 8; ++j) {
          int colL = 16 * j + (l & 15);
#pragma unroll
          for (int r = 0; r < 4; ++r) {
            int rowL = wr + 16 * i + (l >> 4) * 4 + r;
            *(unsigned short*)(Cl + rowL * 256 + ((2 * colL) ^ ((rowL & 7) << 4))) =
                f2bf(acc[i][j][r]);
          }
        }
    } else {
      // transposed: Cl[feat 0..127][s_local byte 0..255]; 4 consecutive s -> 8B write
#pragma unroll
      for (int i = 0; i < 2; ++i)
#pragma unroll
        for (int j = 0; j < 8; ++j) {
          int rowL0 = wr + 16 * i + (l >> 4) * 4;
          int colL = 16 * j + (l & 15);
          us4 o;
#pragma unroll
          for (int r = 0; r < 4; ++r) o[r] = f2bf(acc[i][j][r]);
          *(us4*)(Cl + colL * 256 + ((2 * rowL0) ^ ((colL & 7) << 4))) = o;
        }
    }
    asm volatile("s_waitcnt lgkmcnt(0)" ::: "memory");
    __builtin_amdgcn_sched_barrier(0);
    __builtin_amdgcn_s_barrier();
    {
      // coalesced read-out: 2 threads per 256B LDS row, 16B stores
      int o = tid >> 1, h = tid & 1;
      const char* crow = Cl + o * 256;
      char* gdst;
      if (mat < 2) {
        gdst = (char*)qk + (size_t)mat * M_ * 512 + (size_t)(rt * 128 + o) * 512 +
               col0 * 2 + h * 128;
      } else {
        int b = rt >> 5;
        gdst = (char*)vT + (size_t)(b * 256 + col0 + o) * 8192 +
               (size_t)(rt & 31) * 256 + h * 128;
      }
#pragma unroll
      for (int i16 = 0; i16 < 8; ++i16) {
        short8 v = *(const short8*)(crow + ((h * 128 + i16 * 16) ^ ((o & 7) << 4)));
        *(short8*)(gdst + i16 * 16) = v;
      }
    }
    // Cl reuse is protected by the next ct's stage barriers (>=2 barriers before
    // the next Cl write).
  }
}

// ---------------- K2: block-local attention + fused out-proj ----------------
// (unchanged from r5 — measured 100 us)
__global__ __launch_bounds__(256, 2) void k_attn(const unsigned short* __restrict__ q,
                                                 const unsigned short* __restrict__ k,
                                                 const unsigned short* __restrict__ vT,
                                                 const unsigned short* __restrict__ WT,
                                                 const float* __restrict__ bo,
                                                 float* __restrict__ out) {
  __shared__ char kb2[2][32768];    // K [64][256] / Vt [256][64] / O [64][256] / WoT chunk
  __shared__ char pl[64 * 144];     // P [64 rows][64 keys] bf16, row stride 144 B

  int g = blockIdx.x;
  int xcd = g & 7, idx = g >> 3;                 // 160 per XCD
  int nbid = xcd * 80 + (idx >> 1);
  int half = idx & 1;
  int b = nbid >> 5, n = nbid & 31;
  int tid = threadIdx.x, w = tid >> 6, l = tid & 63;
  int hi16 = (l >> 4) * 16;

  int rowbase = b * 4096 + n * 128 + half * 64 + w * 16;
  const char* qrow = (const char*)q + (size_t)(rowbase + (l & 15)) * 512;
  short8 qf[8];
#pragma unroll
  for (int ks = 0; ks < 8; ++ks) qf[ks] = *(const short8*)(qrow + ks * 64 + hi16);

  f32x4 zero4 = {0.f, 0.f, 0.f, 0.f};
  f32x4 oacc[16];
#pragma unroll
  for (int fj = 0; fj < 16; ++fj) oacc[fj] = zero4;
  float einit = (n == 0 || n == 31) ? 8.0f : 0.0f;   // 2 padded chunks * 4 keys/lane
  float dsum[4] = {einit, einit, einit, einit};

  const char* kbase = (const char*)k + (size_t)b * 4096 * 512;
  const char* vtb   = (const char*)vT + (size_t)b * 256 * 8192;
  const char* woT   = (const char*)(WT + 3 * 65536);

  int c0 = (n == 0) ? 2 : 0;                     // valid chunk range (contiguous)
  int c1 = (n == 31) ? 3 : 5;
  int P = (c1 - c0 + 1) * 2;                     // 8 or 12 phases

  auto STAGE = [&](int bufi, int p) {
    int c = c0 + (p >> 1);
    int kg = (n + (c >> 1) - 1) * 128 + (c & 1) * 64;
    char* dst = kb2[bufi];
    if ((p & 1) == 0) {                          // K chunk: [64 keys][256 feats]
#pragma unroll
      for (int j8 = 0; j8 < 8; ++j8) {
        int d = (j8 * 256 + tid) * 16;
        int key = d >> 9;
        int f2 = (d & 511) ^ ((key & 7) << 4);
        glds16(kbase + (size_t)(kg + key) * 512 + f2, dst + d);
      }
    } else {                                     // Vt chunk: [256 feats][64 keys]
#pragma unroll
      for (int j8 = 0; j8 < 8; ++j8) {
        int d = (j8 * 256 + tid) * 16;
        int feat = d >> 7;
        int kx = (d & 127) ^ ((feat & 7) << 4);
        glds16(vtb + (size_t)feat * 8192 + (size_t)kg * 2 + kx, dst + d);
      }
    }
  };

  STAGE(0, 0);

  for (int p = 0; p < P; ++p) {
    int cur = p & 1;
    if (p + 1 < P) {
      STAGE(cur ^ 1, p + 1);
      asm volatile("s_waitcnt vmcnt(8)" ::: "memory");
    } else {
      asm volatile("s_waitcnt vmcnt(0)" ::: "memory");
    }
    __builtin_amdgcn_sched_barrier(0);
    __builtin_amdgcn_s_barrier();

    const char* kv = kb2[cur];
    if ((p & 1) == 0) {
      // QK^T /16, exp, denom, P -> LDS
#pragma unroll
      for (int j = 0; j < 4; ++j) {
        f32x4 s = zero4;
        int key = 16 * j + (l & 15);
        int kb0 = key * 512, km = (key & 7) << 4;
        __builtin_amdgcn_s_setprio(1);
#pragma unroll
        for (int ks = 0; ks < 8; ++ks) {
          short8 kf = *(const short8*)(kv + kb0 + ((ks * 64 + hi16) ^ km));
          s = __builtin_amdgcn_mfma_f32_16x16x32_bf16(qf[ks], kf, s, 0, 0, 0);
        }
        __builtin_amdgcn_s_setprio(0);
#pragma unroll
        for (int r = 0; r < 4; ++r) {
          float pv = __expf(s[r] * 0.0625f);
          dsum[r] += pv;
          int prow = w * 16 + (l >> 4) * 4 + r;
          *(unsigned short*)(pl + prow * 144 + key * 2) = f2bf(pv);
        }
      }
    } else {
      // O += P * V
#pragma unroll
      for (int ks2 = 0; ks2 < 2; ++ks2) {
        short8 pa = *(const short8*)(pl + (w * 16 + (l & 15)) * 144 + ks2 * 64 + hi16);
        __builtin_amdgcn_s_setprio(1);
#pragma unroll
        for (int fj = 0; fj < 16; ++fj) {
          int feat = 16 * fj + (l & 15);
          short8 vf = *(const short8*)(kv + feat * 128 + ((ks2 * 64 + hi16) ^ ((feat & 7) << 4)));
          oacc[fj] = __builtin_amdgcn_mfma_f32_16x16x32_bf16(pa, vf, oacc[fj], 0, 0, 0);
        }
        __builtin_amdgcn_s_setprio(0);
      }
    }
    asm volatile("s_waitcnt lgkmcnt(0)" ::: "memory");
    __builtin_amdgcn_sched_barrier(0);
    __builtin_amdgcn_s_barrier();
  }

  // ---- softmax denominator ----
#pragma unroll
  for (int r = 0; r < 4; ++r) {
    float t = dsum[r];
    t += __shfl_xor(t, 1); t += __shfl_xor(t, 2);
    t += __shfl_xor(t, 4); t += __shfl_xor(t, 8);
    dsum[r] = 1.0f / t;
  }

  // ---- fused out-proj: O(bf16) -> kb2[0]; WoT chunks -> kb2[1]; out = O@Wo + bo ----
  char* OL = kb2[0];
#pragma unroll
  for (int fj = 0; fj < 16; ++fj) {
    int c2 = 2 * (16 * fj + (l & 15));
#pragma unroll
    for (int r = 0; r < 4; ++r) {
      int qr = w * 16 + (l >> 4) * 4 + r;
      *(unsigned short*)(OL + qr * 512 + (c2 ^ ((qr & 7) << 4))) =
          f2bf(oacc[fj][r] * dsum[r]);
    }
  }

  auto STAGE_WO = [&](int kc) {                  // WoT[n][k] chunk: [256 n][128 B]
#pragma unroll
    for (int j8 = 0; j8 < 8; ++j8) {
      int d = (j8 * 256 + tid) * 16;
      int nrow = d >> 7;
      int kx = (d & 127) ^ ((nrow & 7) << 4);
      glds16(woT + (size_t)nrow * 512 + kc * 128 + kx, kb2[1] + d);
    }
  };

  f32x4 acc2[16];
#pragma unroll
  for (int j = 0; j < 16; ++j) acc2[j] = zero4;

  STAGE_WO(0);
  for (int kc = 0; kc < 4; ++kc) {
    asm volatile("s_waitcnt vmcnt(0)" ::: "memory");
    __builtin_amdgcn_sched_barrier(0);
    __builtin_amdgcn_s_barrier();
#pragma unroll
    for (int kstep = 0; kstep < 2; ++kstep) {
      int qr = w * 16 + (l & 15);
      short8 af = *(const short8*)(OL + qr * 512 +
                    ((kc * 128 + kstep * 64 + hi16) ^ ((qr & 7) << 4)));
      __builtin_amdgcn_s_setprio(1);
#pragma unroll
      for (int j = 0; j < 16; ++j) {
        int nr = 16 * j + (l & 15);
        short8 bf = *(const short8*)(kb2[1] + nr * 128 +
                      ((kstep * 64 + hi16) ^ ((nr & 7) << 4)));
        acc2[j] = __builtin_amdgcn_mfma_f32_16x16x32_bf16(af, bf, acc2[j], 0, 0, 0);
      }
      __builtin_amdgcn_s_setprio(0);
    }
    asm volatile("s_waitcnt lgkmcnt(0)" ::: "memory");
    __builtin_amdgcn_sched_barrier(0);
    __builtin_amdgcn_s_barrier();
    if (kc < 3) STAGE_WO(kc + 1);
  }

  // out rows f = n*2560 + b*128 + half*64 + q  (contiguous 64-row span)
  int f0 = n * 2560 + b * 128 + half * 64 + w * 16 + (l >> 4) * 4;
#pragma unroll
  for (int j = 0; j < 16; ++j) {
    int col = 16 * j + (l & 15);
    float bj = bo[col];
#pragma unroll
    for (int r = 0; r < 4; ++r)
      out[(size_t)(f0 + r) * 256 + col] = acc2[j][r] + bj;
  }
}

// ---------------- launch ----------------
extern "C" void kernel_launch(void* const* d_in, const int* in_sizes, int n_in,
                              void* d_out, int out_size, void* d_ws, size_t ws_size,
                              hipStream_t stream) {
  (void)in_sizes; (void)n_in; (void)out_size; (void)ws_size;
  const float* x  = (const float*)d_in[0];
  const float* Wq = (const float*)d_in[1];
  const float* Wk = (const float*)d_in[2];
  const float* Wv = (const float*)d_in[3];
  const float* Wo = (const float*)d_in[4];
  const float* bo = (const float*)d_in[5];

  char* ws = (char*)d_ws;
  unsigned short* qb = (unsigned short*)(ws + OFF_Q);
  unsigned short* kb = (unsigned short*)(ws + OFF_K);
  unsigned short* vT = (unsigned short*)(ws + OFF_V);
  unsigned short* WT = (unsigned short*)(ws + OFF_WT);

  k_convert_w<<<64, 256, 0, stream>>>(Wq, Wk, Wv, Wo, WT);
  k_qkv<<<640, 256, 0, stream>>>(x, WT, qb, vT);             // q,k row-major; v -> vT
  k_attn<<<1280, 256, 0, stream>>>(qb, kb, vT, WT, bo, (float*)d_out);
}